// Round 4
// baseline (7130.224 us; speedup 1.0000x reference)
//
#include <hip/hip_runtime.h>
#include <math.h>

constexpr float LAM = 1.0f;
constexpr int   NIT = 20;
constexpr float TOL = 1e-6f;

typedef float f4 __attribute__((ext_vector_type(4)));

// ---------------- scal layout (floats) ----------------
#define S_RSOLD 0
#define S_BETA  8
#define S_FLAG  16        // int alias
#define S_PAP   32        // [8][256] partial slots for p.Ap
#define S_RS    (32+2048) // [8][256] partial slots for r.r
#define SCAL_F  (32+4096)

__device__ __forceinline__ float dot8v(f4 a0, f4 a1, f4 b0, f4 b1){
  return a0[0]*b0[0] + a0[1]*b0[1] + a0[2]*b0[2] + a0[3]*b0[3]
       + a1[0]*b1[0] + a1[1]*b1[1] + a1[2]*b1[2] + a1[3]*b1[3];
}

// zero scal, zero cursor
__global__ void k_setup_nm(float* __restrict__ scal, int* __restrict__ cursor, int Mn){
  int i = blockIdx.x * blockDim.x + threadIdx.x;
  int stride = gridDim.x * blockDim.x;
  for (int j = i; j < SCAL_F; j += stride) scal[j] = 0.f;
  for (int j = i; j < Mn; j += stride) cursor[j] = 0;
}

__global__ void k_deg(const int* __restrict__ src, const int* __restrict__ dst,
                      int* __restrict__ cnt, int E){
  int i = blockIdx.x * blockDim.x + threadIdx.x;
  int stride = gridDim.x * blockDim.x;
  for (int e = i; e < E; e += stride){
    atomicAdd(&cnt[src[e]], 1);
    atomicAdd(&cnt[dst[e]], 1);
  }
}

// single block of 1024: exclusive scan cnt -> rowptr, cursor=rowptr
__global__ void k_scan(int* __restrict__ cnt, int* __restrict__ rowptr,
                       int* __restrict__ cursor, int Mn, int twoE){
  __shared__ int sm[1024];
  const int T = 1024;
  int t = threadIdx.x;
  int chunk = (Mn + T - 1) / T;
  int lo = t * chunk, hi = lo + chunk; if (hi > Mn) hi = Mn;
  int s = 0;
  for (int i = lo; i < hi; ++i) s += cnt[i];
  sm[t] = s;
  __syncthreads();
  for (int o = 1; o < T; o <<= 1){
    int v = (t >= o) ? sm[t - o] : 0;
    __syncthreads();
    sm[t] += v;
    __syncthreads();
  }
  int base = (t == 0) ? 0 : sm[t - 1];
  for (int i = lo; i < hi; ++i){
    int c = cnt[i];
    rowptr[i] = base;
    cursor[i] = base;
    base += c;
  }
  if (t == T - 1) rowptr[Mn] = twoE;
}

// fill CSR slots: col[slot] = partner node, es[slot] = (e<<1)|side
__global__ void k_fill(const int* __restrict__ src, const int* __restrict__ dst,
                       int* __restrict__ cursor, int* __restrict__ col,
                       int* __restrict__ es, int E){
  int i = blockIdx.x * blockDim.x + threadIdx.x;
  int stride = gridDim.x * blockDim.x;
  for (int e = i; e < E; e += stride){
    int s = src[e], t = dst[e];
    int ps = atomicAdd(&cursor[s], 1);
    col[ps] = t; es[ps] = (e << 1);
    int pt = atomicAdd(&cursor[t], 1);
    col[pt] = s; es[pt] = (e << 1) | 1;
  }
}

// wave per node (lane l = (d1,d2)): Bcsr[j] = -LAM * X^T Y ; D_v = I + LAM*sum X^T X
// side0 (v=src): X=Rs,Y=Rd.  side1 (v=dst): X=Rd,Y=Rs.  No atomics.
__global__ void k_buildg(const float* __restrict__ Rs, const float* __restrict__ Rd,
                         const int* __restrict__ rowptr, const int* __restrict__ es,
                         float* __restrict__ Bcsr, float* __restrict__ D, int Mn){
  int g = blockIdx.x * blockDim.x + threadIdx.x;
  int v = g >> 6;
  if (v >= Mn) return;
  int l = g & 63, d1 = l >> 3, d2 = l & 7;
  float Dacc = 0.f;
  int j0 = rowptr[v], j1 = rowptr[v + 1];
  int j = j0;
  for (; j + 2 <= j1; j += 2){
    int e0 = es[j], e1 = es[j + 1];
    float ra0 = Rs[(size_t)(e0 >> 1) * 64 + l];
    float rb0 = Rd[(size_t)(e0 >> 1) * 64 + l];
    float ra1 = Rs[(size_t)(e1 >> 1) * 64 + l];
    float rb1 = Rd[(size_t)(e1 >> 1) * 64 + l];
    float x0 = (e0 & 1) ? rb0 : ra0, y0 = (e0 & 1) ? ra0 : rb0;
    float x1 = (e1 & 1) ? rb1 : ra1, y1 = (e1 & 1) ? ra1 : rb1;
    float B0 = 0.f, B1 = 0.f;
    #pragma unroll
    for (int a = 0; a < 8; ++a){
      float p0 = __shfl(x0, a * 8 + d1, 64);
      float q0 = __shfl(y0, a * 8 + d2, 64);
      float s0 = __shfl(x0, a * 8 + d2, 64);
      float p1 = __shfl(x1, a * 8 + d1, 64);
      float q1 = __shfl(y1, a * 8 + d2, 64);
      float s1 = __shfl(x1, a * 8 + d2, 64);
      B0 += p0 * q0;  Dacc += p0 * s0;
      B1 += p1 * q1;  Dacc += p1 * s1;
    }
    __builtin_nontemporal_store(-LAM * B0, &Bcsr[(size_t)j * 64 + l]);
    __builtin_nontemporal_store(-LAM * B1, &Bcsr[(size_t)(j + 1) * 64 + l]);
  }
  for (; j < j1; ++j){
    int e0 = es[j];
    float ra = Rs[(size_t)(e0 >> 1) * 64 + l];
    float rb = Rd[(size_t)(e0 >> 1) * 64 + l];
    float x = (e0 & 1) ? rb : ra, y = (e0 & 1) ? ra : rb;
    float B0 = 0.f;
    #pragma unroll
    for (int a = 0; a < 8; ++a){
      float p0 = __shfl(x, a * 8 + d1, 64);
      float q0 = __shfl(y, a * 8 + d2, 64);
      float s0 = __shfl(x, a * 8 + d2, 64);
      B0 += p0 * q0;  Dacc += p0 * s0;
    }
    __builtin_nontemporal_store(-LAM * B0, &Bcsr[(size_t)j * 64 + l]);
  }
  D[(size_t)v * 64 + l] = ((d1 == d2) ? 1.f : 0.f) + LAM * Dacc;
}

// wave per node, lane l=(b*8+dd): Ap[v] = D_v p_v + sum_j Bcsr[j] p_col[j]
// Bcsr streamed with nontemporal loads (keep p/D resident in LLC).
// fused: accumulates p.Ap partials into S_PAP slots.
__global__ void k_mv(const float* __restrict__ D, const float* __restrict__ Bcsr,
                     const int* __restrict__ rowptr, const int* __restrict__ col,
                     const float* __restrict__ p, float* __restrict__ out,
                     float* __restrict__ scal, int Mn){
  if (*(const int*)(scal + S_FLAG)) return;
  int g = blockIdx.x * blockDim.x + threadIdx.x;
  int v = g >> 6;
  if (v >= Mn) return;
  int l = g & 63, b = l >> 3, dd = l & 7;
  const f4* pv4 = (const f4*)(p + (size_t)v * 64 + b * 8);
  f4 pv0 = pv4[0], pv1 = pv4[1];
  const f4* dr4 = (const f4*)(D + (size_t)v * 64 + dd * 8);
  float acc = dot8v(dr4[0], dr4[1], pv0, pv1);
  int j0 = rowptr[v], j1 = rowptr[v + 1];
  int j = j0;
  for (; j + 4 <= j1; j += 4){
    int c0 = col[j], c1 = col[j + 1], c2 = col[j + 2], c3 = col[j + 3];
    const f4* B0 = (const f4*)(Bcsr + (size_t)j * 64 + dd * 8);
    f4 m00 = __builtin_nontemporal_load(B0);
    f4 m01 = __builtin_nontemporal_load(B0 + 1);
    f4 m10 = __builtin_nontemporal_load(B0 + 16);
    f4 m11 = __builtin_nontemporal_load(B0 + 17);
    f4 m20 = __builtin_nontemporal_load(B0 + 32);
    f4 m21 = __builtin_nontemporal_load(B0 + 33);
    f4 m30 = __builtin_nontemporal_load(B0 + 48);
    f4 m31 = __builtin_nontemporal_load(B0 + 49);
    const f4* q0 = (const f4*)(p + (size_t)c0 * 64 + b * 8);
    const f4* q1 = (const f4*)(p + (size_t)c1 * 64 + b * 8);
    const f4* q2 = (const f4*)(p + (size_t)c2 * 64 + b * 8);
    const f4* q3 = (const f4*)(p + (size_t)c3 * 64 + b * 8);
    f4 a0 = q0[0], a1 = q0[1];
    f4 b0 = q1[0], b1 = q1[1];
    f4 e0 = q2[0], e1 = q2[1];
    f4 f0 = q3[0], f1 = q3[1];
    acc += dot8v(m00, m01, a0, a1);
    acc += dot8v(m10, m11, b0, b1);
    acc += dot8v(m20, m21, e0, e1);
    acc += dot8v(m30, m31, f0, f1);
  }
  for (; j < j1; ++j){
    int c = col[j];
    const f4* B0 = (const f4*)(Bcsr + (size_t)j * 64 + dd * 8);
    f4 m0 = __builtin_nontemporal_load(B0);
    f4 m1 = __builtin_nontemporal_load(B0 + 1);
    const f4* q = (const f4*)(p + (size_t)c * 64 + b * 8);
    f4 g0 = q[0], g1 = q[1];
    acc += dot8v(m0, m1, g0, g1);
  }
  out[(size_t)v * 64 + l] = acc;
  // fused p.Ap partial
  float pself = (dd & 4) ? ((dd & 2) ? ((dd & 1) ? pv1[3] : pv1[2])
                                     : ((dd & 1) ? pv1[1] : pv1[0]))
                         : ((dd & 2) ? ((dd & 1) ? pv0[3] : pv0[2])
                                     : ((dd & 1) ? pv0[1] : pv0[0]));
  float part = pself * acc;
  part += __shfl_xor(part, 1, 64);
  part += __shfl_xor(part, 2, 64);
  part += __shfl_xor(part, 4, 64);
  if (dd == 0)
    atomicAdd(&scal[S_PAP + b * 256 + (blockIdx.x & 255)], part);
}

// c0 (batch-major) -> node-major buffer
__global__ void k_perm(const float* __restrict__ c0, float* __restrict__ xp, int Mn){
  int i = blockIdx.x * blockDim.x + threadIdx.x;
  int n4 = Mn * 16;
  if (i >= n4) return;
  int v = i >> 4, rem = i & 15, b = rem >> 1, half = rem & 1;
  f4 cv = *(const f4*)(c0 + ((size_t)b * Mn + v) * 8 + half * 4);
  ((f4*)xp)[i] = cv;
}

// r = c0p - Ap; p = r (in place over c0p); x (batch-major, d_out) = c0;
// accumulate r.r into S_RS slots
__global__ void k_init_nm(float* __restrict__ p, const float* __restrict__ Ap,
                          float* __restrict__ r, float* __restrict__ x_bm,
                          float* __restrict__ scal, int n4tot, int Mn){
  int i = blockIdx.x * blockDim.x + threadIdx.x;
  int l = threadIdx.x & 63;
  float part = 0.f;
  if (i < n4tot){
    f4 cv = ((const f4*)p)[i];
    f4 av = ((const f4*)Ap)[i];
    f4 rv = cv - av;
    ((f4*)r)[i] = rv;
    ((f4*)p)[i] = rv;
    int v = i >> 4, rem = i & 15, b = rem >> 1, half = rem & 1;
    ((f4*)x_bm)[((size_t)b * Mn + v) * 2 + half] = cv;
    part = rv[0]*rv[0] + rv[1]*rv[1] + rv[2]*rv[2] + rv[3]*rv[3];
  }
  part += __shfl_xor(part, 1, 64);
  part += __shfl_xor(part, 16, 64);
  part += __shfl_xor(part, 32, 64);
  if ((l & 49) == 0)
    atomicAdd(&scal[S_RS + ((l >> 1) & 7) * 256 + (blockIdx.x & 255)], part);
}

// once: RSOLD[b] = sum(S_RS slots); zero both slot arrays
__global__ void k_s0(float* __restrict__ scal){
  __shared__ float sm[256];
  int t = threadIdx.x;
  int b = t >> 5, k0 = t & 31;
  float s = 0.f;
  #pragma unroll
  for (int i = 0; i < 8; ++i) s += scal[S_RS + b * 256 + k0 + i * 32];
  sm[t] = s;
  __syncthreads();
  if (t < 8){
    float tot = 0.f;
    #pragma unroll
    for (int i = 0; i < 32; ++i) tot += sm[t * 32 + i];
    scal[S_RSOLD + t] = tot;
  }
  __syncthreads();
  for (int i = t; i < 4096; i += 256) scal[S_PAP + i] = 0.f;
}

// x(batch-major) += a p; r -= a Ap; accumulate rnew.rnew (alpha from S_PAP slots)
__global__ void k_upd_nm(float* __restrict__ x_bm, float* __restrict__ r,
                         const float* __restrict__ p, const float* __restrict__ Ap,
                         float* __restrict__ scal, int n4tot, int Mn){
  if (*(const int*)(scal + S_FLAG)) return;
  __shared__ float sal[8];
  int t = threadIdx.x;
  if (t < 8){
    float s = 0.f;
    const float* pp = scal + S_PAP + t * 256;
    #pragma unroll 4
    for (int k = 0; k < 256; ++k) s += pp[k];
    sal[t] = scal[S_RSOLD + t] / (s + 1e-12f);
  }
  __syncthreads();
  int i = blockIdx.x * blockDim.x + t;
  int l = t & 63;
  float part = 0.f;
  if (i < n4tot){
    int v = i >> 4, rem = i & 15, b = rem >> 1, half = rem & 1;
    float al = sal[b];
    size_t xi = ((size_t)b * Mn + v) * 2 + half;
    f4 pv = ((const f4*)p)[i];
    f4 av = ((const f4*)Ap)[i];
    f4 xv = ((f4*)x_bm)[xi];
    f4 rv = ((f4*)r)[i];
    xv += al * pv;
    rv -= al * av;
    ((f4*)x_bm)[xi] = xv;
    ((f4*)r)[i] = rv;
    part = rv[0]*rv[0] + rv[1]*rv[1] + rv[2]*rv[2] + rv[3]*rv[3];
  }
  part += __shfl_xor(part, 1, 64);
  part += __shfl_xor(part, 16, 64);
  part += __shfl_xor(part, 32, 64);
  if ((l & 49) == 0)
    atomicAdd(&scal[S_RS + ((l >> 1) & 7) * 256 + (blockIdx.x & 255)], part);
}

// rsnew from S_RS; conv check/flag; BETA, RSOLD; zero slot arrays
__global__ void k_s2(float* __restrict__ scal){
  if (*(const int*)(scal + S_FLAG)) return;
  __shared__ float sm[256];
  __shared__ float rsn[8];
  int t = threadIdx.x;
  int b = t >> 5, k0 = t & 31;
  float s = 0.f;
  #pragma unroll
  for (int i = 0; i < 8; ++i) s += scal[S_RS + b * 256 + k0 + i * 32];
  sm[t] = s;
  __syncthreads();
  if (t < 8){
    float tot = 0.f;
    #pragma unroll
    for (int i = 0; i < 32; ++i) tot += sm[t * 32 + i];
    rsn[t] = tot;
  }
  __syncthreads();
  if (t == 0){
    float ssum = 0.f;
    for (int bb = 0; bb < 8; ++bb) ssum += rsn[bb];
    if (sqrtf(ssum / 8.0f) < TOL){
      *(int*)(scal + S_FLAG) = 1;   // freeze
    } else {
      for (int bb = 0; bb < 8; ++bb){
        scal[S_BETA + bb]  = rsn[bb] / (scal[S_RSOLD + bb] + 1e-12f);
        scal[S_RSOLD + bb] = rsn[bb];
      }
    }
  }
  __syncthreads();
  for (int i = t; i < 4096; i += 256) scal[S_PAP + i] = 0.f;
}

__global__ void k_pupd_nm(const float* __restrict__ r, float* __restrict__ p,
                          const float* __restrict__ scal, int n4tot){
  if (*(const int*)(scal + S_FLAG)) return;
  int i = blockIdx.x * blockDim.x + threadIdx.x;
  if (i >= n4tot) return;
  int b = (i >> 1) & 7;
  float be = scal[S_BETA + b];
  f4 rv = ((const f4*)r)[i];
  f4 pv = ((f4*)p)[i];
  pv = rv + be * pv;
  ((f4*)p)[i] = pv;
}

// ---------------- minimal fallback tier (batch-major, R-direct) ----------------
#define OS_RSOLD 0
#define OS_PAP   8
#define OS_RSNEW 16
#define OS_ALPHA 24
#define OS_BETA  32
#define OS_FLAG  40

__device__ __forceinline__ float blk_reduce_256(float v){
  __shared__ float sm[4];
  #pragma unroll
  for (int o = 32; o > 0; o >>= 1) v += __shfl_down(v, o, 64);
  int lane = threadIdx.x & 63, w = threadIdx.x >> 6;
  if (lane == 0) sm[w] = v;
  __syncthreads();
  return (threadIdx.x == 0) ? (sm[0] + sm[1] + sm[2] + sm[3]) : 0.f;
}

__global__ void k_setup_fb(float* scal){
  int i = blockIdx.x * blockDim.x + threadIdx.x;
  if (i < 64) scal[i] = 0.f;
}

__global__ void k_apinit(const float* __restrict__ in, float* __restrict__ out,
                         int n4tot, const int* __restrict__ flag){
  if (*flag) return;
  int j = blockIdx.x * blockDim.x + threadIdx.x;
  if (j < n4tot) ((f4*)out)[j] = ((const f4*)in)[j];
}

__global__ void k_mv_edge_fb(const float* __restrict__ Rs, const float* __restrict__ Rd,
                             const int* __restrict__ src, const int* __restrict__ dst,
                             const float* __restrict__ in, float* __restrict__ out,
                             int Mn, int E, const int* __restrict__ flag){
  if (*flag) return;
  int g  = blockIdx.x * blockDim.x + threadIdx.x;
  int wv = g >> 6, l = g & 63;
  int nw = (gridDim.x * blockDim.x) >> 6;
  int b = l >> 3, q = l & 7;
  for (int e = wv; e < E; e += nw){
    int s = src[e], t = dst[e];
    const f4* rs4 = (const f4*)(Rs + (size_t)e * 64 + q * 8);
    const f4* rd4 = (const f4*)(Rd + (size_t)e * 64 + q * 8);
    const f4* ps4 = (const f4*)(in + ((size_t)b * Mn + s) * 8);
    const f4* pd4 = (const f4*)(in + ((size_t)b * Mn + t) * 8);
    f4 ra0 = rs4[0], ra1 = rs4[1], pa0 = ps4[0], pa1 = ps4[1];
    f4 rb0 = rd4[0], rb1 = rd4[1], pb0 = pd4[0], pb1 = pd4[1];
    float re = dot8v(ra0, ra1, pa0, pa1) - dot8v(rb0, rb1, pb0, pb1);
    float cs = 0.f, cd = 0.f;
    #pragma unroll
    for (int a = 0; a < 8; ++a){
      float rea = __shfl(re, b * 8 + a, 64);
      cs += Rs[(size_t)e * 64 + a * 8 + q] * rea;
      cd += Rd[(size_t)e * 64 + a * 8 + q] * rea;
    }
    atomicAdd(&out[((size_t)b * Mn + s) * 8 + q],  LAM * cs);
    atomicAdd(&out[((size_t)b * Mn + t) * 8 + q], -LAM * cd);
  }
}

__global__ void k_init_o(const float* __restrict__ c0, const float* __restrict__ Ap,
                         float* __restrict__ x, float* __restrict__ r, float* __restrict__ p,
                         float* scal, int n4){
  int b = blockIdx.y;
  size_t base = (size_t)b * n4;
  int j = blockIdx.x * blockDim.x + threadIdx.x;
  float part = 0.f;
  if (j < n4){
    f4 cv = ((const f4*)c0)[base + j];
    f4 av = ((const f4*)Ap)[base + j];
    f4 rv = cv - av;
    ((f4*)x)[base + j] = cv;
    ((f4*)r)[base + j] = rv;
    ((f4*)p)[base + j] = rv;
    part = rv[0]*rv[0] + rv[1]*rv[1] + rv[2]*rv[2] + rv[3]*rv[3];
  }
  float tot = blk_reduce_256(part);
  if (threadIdx.x == 0) atomicAdd(&scal[OS_RSOLD + b], tot);
}

__global__ void k_dot_o(const float* __restrict__ p, const float* __restrict__ Ap,
                        float* scal, int n4){
  const int* flag = (const int*)(scal + OS_FLAG);
  if (*flag) return;
  int b = blockIdx.y;
  size_t base = (size_t)b * n4;
  int j = blockIdx.x * blockDim.x + threadIdx.x;
  float part = 0.f;
  if (j < n4){
    f4 pv = ((const f4*)p)[base + j];
    f4 av = ((const f4*)Ap)[base + j];
    part = pv[0]*av[0] + pv[1]*av[1] + pv[2]*av[2] + pv[3]*av[3];
  }
  float tot = blk_reduce_256(part);
  if (threadIdx.x == 0) atomicAdd(&scal[OS_PAP + b], tot);
}

__global__ void k_s1_o(float* scal){
  const int* flag = (const int*)(scal + OS_FLAG);
  if (*flag) return;
  int t = threadIdx.x;
  if (t < 8){
    scal[OS_ALPHA + t] = scal[OS_RSOLD + t] / (scal[OS_PAP + t] + 1e-12f);
    scal[OS_RSNEW + t] = 0.f;
  }
}

__global__ void k_upd_o(float* __restrict__ x, float* __restrict__ r,
                        const float* __restrict__ p, const float* __restrict__ Ap,
                        float* scal, int n4){
  const int* flag = (const int*)(scal + OS_FLAG);
  if (*flag) return;
  int b = blockIdx.y;
  size_t base = (size_t)b * n4;
  float al = scal[OS_ALPHA + b];
  int j = blockIdx.x * blockDim.x + threadIdx.x;
  float part = 0.f;
  if (j < n4){
    f4 pv = ((const f4*)p)[base + j];
    f4 av = ((const f4*)Ap)[base + j];
    f4 xv = ((f4*)x)[base + j];
    f4 rv = ((f4*)r)[base + j];
    xv += al * pv;
    rv -= al * av;
    ((f4*)x)[base + j] = xv;
    ((f4*)r)[base + j] = rv;
    part = rv[0]*rv[0] + rv[1]*rv[1] + rv[2]*rv[2] + rv[3]*rv[3];
  }
  float tot = blk_reduce_256(part);
  if (threadIdx.x == 0) atomicAdd(&scal[OS_RSNEW + b], tot);
}

__global__ void k_s2_o(float* scal){
  int* flag = (int*)(scal + OS_FLAG);
  if (*flag) return;
  if (threadIdx.x == 0){
    float ssum = 0.f;
    for (int bb = 0; bb < 8; ++bb) ssum += scal[OS_RSNEW + bb];
    if (sqrtf(ssum / 8.0f) < TOL){
      *flag = 1;
    } else {
      for (int bb = 0; bb < 8; ++bb){
        scal[OS_BETA + bb]  = scal[OS_RSNEW + bb] / (scal[OS_RSOLD + bb] + 1e-12f);
        scal[OS_RSOLD + bb] = scal[OS_RSNEW + bb];
        scal[OS_PAP + bb]   = 0.f;
      }
    }
  }
}

__global__ void k_pupd_o(const float* __restrict__ r, float* __restrict__ p,
                         float* scal, int n4){
  const int* flag = (const int*)(scal + OS_FLAG);
  if (*flag) return;
  int b = blockIdx.y;
  size_t base = (size_t)b * n4;
  float be = scal[OS_BETA + b];
  int j = blockIdx.x * blockDim.x + threadIdx.x;
  if (j < n4){
    f4 rv = ((const f4*)r)[base + j];
    f4 pv = ((f4*)p)[base + j];
    pv = rv + be * pv;
    ((f4*)p)[base + j] = pv;
  }
}

// ---------------- launch ----------------
extern "C" void kernel_launch(void* const* d_in, const int* in_sizes, int n_in,
                              void* d_out, int out_size, void* d_ws, size_t ws_size,
                              hipStream_t stream){
  const float* c0  = (const float*)d_in[0];
  const int*   src = (const int*)d_in[1];
  const int*   dst = (const int*)d_in[2];
  const float* Rs  = (const float*)d_in[3];
  const float* Rd  = (const float*)d_in[4];

  int N  = in_sizes[0];          // B*Mn*8 floats, B=8, d=8
  int Mn = N / 64;
  int E  = in_sizes[1];
  int n4tot = N / 4;
  int twoE = 2 * E;

  float* ws = (float*)d_ws;
  size_t off = 0;
  float* r    = ws + off;  off += N;
  float* p    = ws + off;  off += N;
  float* Ap   = ws + off;  off += N;
  float* scal = ws + off;  off += SCAL_F;
  float* D    = ws + off;  off += (size_t)Mn * 64;
  int* rowptr = (int*)(ws + off);  off += (size_t)((Mn + 1 + 3) & ~3);
  int* cursor = (int*)(ws + off);  off += (size_t)((Mn + 3) & ~3);
  int* colA   = (int*)(ws + off);  off += (size_t)twoE;
  int* esA    = (int*)(ws + off);  off += (size_t)twoE;
  float* Bcsr = ws + off;  off += (size_t)twoE * 64;
  size_t need_main = off * 4;

  int nb_vec  = (n4tot + 255) / 256;
  int nb_node = (Mn * 64 + 255) / 256;

  if (ws_size >= need_main){
    k_setup_nm<<<512, 256, 0, stream>>>(scal, cursor, Mn);
    k_deg  <<<1024, 256, 0, stream>>>(src, dst, cursor, E);
    k_scan <<<1, 1024, 0, stream>>>(cursor, rowptr, cursor, Mn, twoE);
    k_fill <<<1024, 256, 0, stream>>>(src, dst, cursor, colA, esA, E);
    k_buildg<<<nb_node, 256, 0, stream>>>(Rs, Rd, rowptr, esA, Bcsr, D, Mn);

    float* x_bm = (float*)d_out;
    k_perm<<<nb_vec, 256, 0, stream>>>(c0, p, Mn);              // p := c0 (node-major)
    k_mv<<<nb_node, 256, 0, stream>>>(D, Bcsr, rowptr, colA, p, Ap, scal, Mn);
    k_init_nm<<<nb_vec, 256, 0, stream>>>(p, Ap, r, x_bm, scal, n4tot, Mn);
    k_s0<<<1, 256, 0, stream>>>(scal);

    for (int it = 0; it < NIT; ++it){
      k_mv<<<nb_node, 256, 0, stream>>>(D, Bcsr, rowptr, colA, p, Ap, scal, Mn);
      k_upd_nm<<<nb_vec, 256, 0, stream>>>(x_bm, r, p, Ap, scal, n4tot, Mn);
      k_s2<<<1, 256, 0, stream>>>(scal);
      k_pupd_nm<<<nb_vec, 256, 0, stream>>>(r, p, scal, n4tot);
    }
  } else {
    // fallback: batch-major R-direct (needs 3N+64 floats)
    float* fr    = ws;
    float* fp    = fr + N;
    float* fAp   = fp + N;
    float* fscal = fAp + N;
    const int* flagp = (const int*)(fscal + OS_FLAG);
    int n4 = Mn * 2;
    dim3 vgrid((n4 + 255) / 256, 8);
    int cb = (n4tot + 255) / 256;
    float* x = (float*)d_out;

    k_setup_fb<<<1, 64, 0, stream>>>(fscal);
    k_apinit<<<cb, 256, 0, stream>>>(c0, fAp, n4tot, flagp);
    k_mv_edge_fb<<<2048, 256, 0, stream>>>(Rs, Rd, src, dst, c0, fAp, Mn, E, flagp);
    k_init_o<<<vgrid, 256, 0, stream>>>(c0, fAp, x, fr, fp, fscal, n4);
    for (int it = 0; it < NIT; ++it){
      k_apinit<<<cb, 256, 0, stream>>>(fp, fAp, n4tot, flagp);
      k_mv_edge_fb<<<2048, 256, 0, stream>>>(Rs, Rd, src, dst, fp, fAp, Mn, E, flagp);
      k_dot_o<<<vgrid, 256, 0, stream>>>(fp, fAp, fscal, n4);
      k_s1_o<<<1, 64, 0, stream>>>(fscal);
      k_upd_o<<<vgrid, 256, 0, stream>>>(x, fr, fp, fAp, fscal, n4);
      k_s2_o<<<1, 64, 0, stream>>>(fscal);
      k_pupd_o<<<vgrid, 256, 0, stream>>>(fr, fp, fscal, n4);
    }
  }
}

// Round 5
// 5763.140 us; speedup vs baseline: 1.2372x; 1.2372x over previous
//
#include <hip/hip_runtime.h>
#include <math.h>

constexpr float LAM = 1.0f;
constexpr int   NIT = 20;
constexpr float TOL = 1e-6f;

typedef float f4 __attribute__((ext_vector_type(4)));

// ---------------- scal layout (floats) ----------------
#define S_RSOLD 0
#define S_ALPHA 8
#define S_BETA  16
#define S_FLAG  24        // int alias
#define S_PAP   32        // [8][256] partial slots for p.Ap
#define S_RS    (32+2048) // [8][256] partial slots for r.r
#define SCAL_F  (32+4096)

__device__ __forceinline__ float dot8v(f4 a0, f4 a1, f4 b0, f4 b1){
  return a0[0]*b0[0] + a0[1]*b0[1] + a0[2]*b0[2] + a0[3]*b0[3]
       + a1[0]*b1[0] + a1[1]*b1[1] + a1[2]*b1[2] + a1[3]*b1[3];
}

// zero scal, zero cursor
__global__ void k_setup_nm(float* __restrict__ scal, int* __restrict__ cursor, int Mn){
  int i = blockIdx.x * blockDim.x + threadIdx.x;
  int stride = gridDim.x * blockDim.x;
  for (int j = i; j < SCAL_F; j += stride) scal[j] = 0.f;
  for (int j = i; j < Mn; j += stride) cursor[j] = 0;
}

__global__ void k_deg(const int* __restrict__ src, const int* __restrict__ dst,
                      int* __restrict__ cnt, int E){
  int i = blockIdx.x * blockDim.x + threadIdx.x;
  int stride = gridDim.x * blockDim.x;
  for (int e = i; e < E; e += stride){
    atomicAdd(&cnt[src[e]], 1);
    atomicAdd(&cnt[dst[e]], 1);
  }
}

// exclusive scan (deg+1 per node: slot 0 of each row is the diagonal block)
// rowptr[i] = base; cursor[i] = base+1 (neighbors start after diag); rowptr[Mn]=tot
__global__ void k_scan(int* __restrict__ cnt, int* __restrict__ rowptr,
                       int* __restrict__ cursor, int Mn, int tot){
  __shared__ int sm[1024];
  const int T = 1024;
  int t = threadIdx.x;
  int chunk = (Mn + T - 1) / T;
  int lo = t * chunk, hi = lo + chunk; if (hi > Mn) hi = Mn;
  int s = 0;
  for (int i = lo; i < hi; ++i) s += cnt[i] + 1;
  sm[t] = s;
  __syncthreads();
  for (int o = 1; o < T; o <<= 1){
    int v = (t >= o) ? sm[t - o] : 0;
    __syncthreads();
    sm[t] += v;
    __syncthreads();
  }
  int base = (t == 0) ? 0 : sm[t - 1];
  for (int i = lo; i < hi; ++i){
    int c = cnt[i];
    rowptr[i] = base;
    cursor[i] = base + 1;
    base += c + 1;
  }
  if (t == T - 1) rowptr[Mn] = tot;
}

// fill CSR neighbor slots: col[slot]=partner, es[slot]=(e<<1)|side
__global__ void k_fill(const int* __restrict__ src, const int* __restrict__ dst,
                       int* __restrict__ cursor, int* __restrict__ col,
                       int* __restrict__ es, int E){
  int i = blockIdx.x * blockDim.x + threadIdx.x;
  int stride = gridDim.x * blockDim.x;
  for (int e = i; e < E; e += stride){
    int s = src[e], t = dst[e];
    int ps = atomicAdd(&cursor[s], 1);
    col[ps] = t; es[ps] = (e << 1);
    int pt = atomicAdd(&cursor[t], 1);
    col[pt] = s; es[pt] = (e << 1) | 1;
  }
}

// wave per node (lane l=(d1,d2)): neighbor slots j in (j0,j1): Bcsr[j] = -LAM*X^T Y.
// Diagonal slot j0: Bcsr[j0] = I + LAM*sum X^T X, col[j0] = v. No atomics.
__global__ void k_buildg(const float* __restrict__ Rs, const float* __restrict__ Rd,
                         const int* __restrict__ rowptr, const int* __restrict__ es,
                         float* __restrict__ Bcsr, int* __restrict__ col, int Mn){
  int g = blockIdx.x * blockDim.x + threadIdx.x;
  int v = g >> 6;
  if (v >= Mn) return;
  int l = g & 63, d1 = l >> 3, d2 = l & 7;
  float Dacc = 0.f;
  int j0 = rowptr[v], j1 = rowptr[v + 1];
  int j = j0 + 1;
  for (; j + 2 <= j1; j += 2){
    int e0 = es[j], e1 = es[j + 1];
    float ra0 = Rs[(size_t)(e0 >> 1) * 64 + l];
    float rb0 = Rd[(size_t)(e0 >> 1) * 64 + l];
    float ra1 = Rs[(size_t)(e1 >> 1) * 64 + l];
    float rb1 = Rd[(size_t)(e1 >> 1) * 64 + l];
    float x0 = (e0 & 1) ? rb0 : ra0, y0 = (e0 & 1) ? ra0 : rb0;
    float x1 = (e1 & 1) ? rb1 : ra1, y1 = (e1 & 1) ? ra1 : rb1;
    float B0 = 0.f, B1 = 0.f;
    #pragma unroll
    for (int a = 0; a < 8; ++a){
      float p0 = __shfl(x0, a * 8 + d1, 64);
      float q0 = __shfl(y0, a * 8 + d2, 64);
      float s0 = __shfl(x0, a * 8 + d2, 64);
      float p1 = __shfl(x1, a * 8 + d1, 64);
      float q1 = __shfl(y1, a * 8 + d2, 64);
      float s1 = __shfl(x1, a * 8 + d2, 64);
      B0 += p0 * q0;  Dacc += p0 * s0;
      B1 += p1 * q1;  Dacc += p1 * s1;
    }
    __builtin_nontemporal_store(-LAM * B0, &Bcsr[(size_t)j * 64 + l]);
    __builtin_nontemporal_store(-LAM * B1, &Bcsr[(size_t)(j + 1) * 64 + l]);
  }
  for (; j < j1; ++j){
    int e0 = es[j];
    float ra = Rs[(size_t)(e0 >> 1) * 64 + l];
    float rb = Rd[(size_t)(e0 >> 1) * 64 + l];
    float x = (e0 & 1) ? rb : ra, y = (e0 & 1) ? ra : rb;
    float B0 = 0.f;
    #pragma unroll
    for (int a = 0; a < 8; ++a){
      float p0 = __shfl(x, a * 8 + d1, 64);
      float q0 = __shfl(y, a * 8 + d2, 64);
      float s0 = __shfl(x, a * 8 + d2, 64);
      B0 += p0 * q0;  Dacc += p0 * s0;
    }
    __builtin_nontemporal_store(-LAM * B0, &Bcsr[(size_t)j * 64 + l]);
  }
  Bcsr[(size_t)j0 * 64 + l] = ((d1 == d2) ? 1.f : 0.f) + LAM * Dacc;
  if (l == 0) col[j0] = v;
}

// wave per node. Two-phase, LDS-staged, double-buffered gather matvec.
// Phase A (lane=(hi,lo)): gather segment lo of p[col[chunk_j+hi]] -> pbuf.
// Phase B (lane=(b,dd)): acc += Bcsr[j][dd,:] . pbuf[j][b,:], B streamed NT.
// fused p.Ap partials into S_PAP slots.
__global__ void k_mv(const float* __restrict__ Bcsr, const int* __restrict__ rowptr,
                     const int* __restrict__ col, const float* __restrict__ p,
                     float* __restrict__ out, float* __restrict__ scal, int Mn){
  if (*(const int*)(scal + S_FLAG)) return;
  __shared__ float pbuf[4][2][8][64];
  __shared__ int   cbuf[4][128];
  int g = blockIdx.x * blockDim.x + threadIdx.x;
  int v = g >> 6;
  bool active = (v < Mn);
  int w  = threadIdx.x >> 6;
  int l  = g & 63;
  int hi = l >> 3, lo = l & 7;
  int k8 = lo * 8;          // phase-A segment offset
  int b8 = hi * 8;          // phase-B batch offset
  int j0 = 0, j1 = 0, rowlen = 0;
  if (active){
    j0 = rowptr[v]; j1 = rowptr[v + 1];
    rowlen = j1 - j0;
    for (int jj = l; jj < rowlen && jj < 128; jj += 64)
      cbuf[w][jj] = col[j0 + jj];
  }
  __syncthreads();
  if (!active) return;

  const int* cb = cbuf[w];
  int nch = (rowlen + 7) >> 3;

  // gather chunk n into (g0,g1)
  auto gather = [&](int n, f4& g0, f4& g1){
    int jj = n * 8 + hi;
    int c = v;
    if (jj < rowlen) c = (jj < 128) ? cb[jj] : col[j0 + jj];
    const float* pc = p + (size_t)c * 64 + k8;
    g0 = *(const f4*)pc;
    g1 = *(const f4*)(pc + 4);
  };

  {
    f4 u0, u1;
    gather(0, u0, u1);
    float* d0 = &pbuf[w][0][hi][k8];
    *(f4*)d0 = u0; *(f4*)(d0 + 4) = u1;
  }

  float acc = 0.f;
  for (int n = 0; n < nch; ++n){
    int nb = n & 1;
    bool more = (n + 1 < nch);
    f4 g0, g1;
    if (more) gather(n + 1, g0, g1);
    int jb = j0 + n * 8;
    #pragma unroll
    for (int q = 0; q < 8; ++q){
      if (jb + q < j1){
        const f4* Bp = (const f4*)(Bcsr + (size_t)(jb + q) * 64 + k8);
        f4 m0 = __builtin_nontemporal_load(Bp);
        f4 m1 = __builtin_nontemporal_load(Bp + 1);
        const float* pr = &pbuf[w][nb][q][b8];
        f4 q0 = *(const f4*)pr;
        f4 q1 = *(const f4*)(pr + 4);
        acc += dot8v(m0, m1, q0, q1);
      }
    }
    if (more){
      float* d1 = &pbuf[w][nb ^ 1][hi][k8];
      *(f4*)d1 = g0; *(f4*)(d1 + 4) = g1;
    }
  }
  out[(size_t)v * 64 + l] = acc;
  // fused p.Ap partial (lane's own p element; hi = batch here)
  float pself = p[(size_t)v * 64 + l];
  float part = pself * acc;
  part += __shfl_xor(part, 1, 64);
  part += __shfl_xor(part, 2, 64);
  part += __shfl_xor(part, 4, 64);
  if (lo == 0)
    atomicAdd(&scal[S_PAP + hi * 256 + (blockIdx.x & 255)], part);
}

// c0 (batch-major) -> node-major buffer
__global__ void k_perm(const float* __restrict__ c0, float* __restrict__ xp, int Mn){
  int i = blockIdx.x * blockDim.x + threadIdx.x;
  int n4 = Mn * 16;
  if (i >= n4) return;
  int v = i >> 4, rem = i & 15, b = rem >> 1, half = rem & 1;
  f4 cv = *(const f4*)(c0 + ((size_t)b * Mn + v) * 8 + half * 4);
  ((f4*)xp)[i] = cv;
}

// r = c0p - Ap; p = r (in place over c0p); x (batch-major, d_out) = c0;
// accumulate r.r into S_RS slots
__global__ void k_init_nm(float* __restrict__ p, const float* __restrict__ Ap,
                          float* __restrict__ r, float* __restrict__ x_bm,
                          float* __restrict__ scal, int n4tot, int Mn){
  int i = blockIdx.x * blockDim.x + threadIdx.x;
  int l = threadIdx.x & 63;
  float part = 0.f;
  if (i < n4tot){
    f4 cv = ((const f4*)p)[i];
    f4 av = ((const f4*)Ap)[i];
    f4 rv = cv - av;
    ((f4*)r)[i] = rv;
    ((f4*)p)[i] = rv;
    int v = i >> 4, rem = i & 15, b = rem >> 1, half = rem & 1;
    ((f4*)x_bm)[((size_t)b * Mn + v) * 2 + half] = cv;
    part = rv[0]*rv[0] + rv[1]*rv[1] + rv[2]*rv[2] + rv[3]*rv[3];
  }
  part += __shfl_xor(part, 1, 64);
  part += __shfl_xor(part, 16, 64);
  part += __shfl_xor(part, 32, 64);
  if ((l & 49) == 0)
    atomicAdd(&scal[S_RS + ((l >> 1) & 7) * 256 + (blockIdx.x & 255)], part);
}

// once: RSOLD[b] = sum(S_RS); zero both slot arrays
__global__ void k_s0(float* __restrict__ scal){
  __shared__ float sm[256];
  int t = threadIdx.x;
  int b = t >> 5, k0 = t & 31;
  float s = 0.f;
  #pragma unroll
  for (int i = 0; i < 8; ++i) s += scal[S_RS + b * 256 + k0 + i * 32];
  sm[t] = s;
  __syncthreads();
  if (t < 8){
    float tot = 0.f;
    #pragma unroll
    for (int i = 0; i < 32; ++i) tot += sm[t * 32 + i];
    scal[S_RSOLD + t] = tot;
  }
  __syncthreads();
  for (int i = t; i < 4096; i += 256) scal[S_PAP + i] = 0.f;
}

// alpha[b] = rsold[b] / (sum S_PAP slots + eps)
__global__ void k_alpha(float* __restrict__ scal){
  if (*(const int*)(scal + S_FLAG)) return;
  __shared__ float sm[256];
  int t = threadIdx.x;
  int b = t >> 5, k0 = t & 31;
  float s = 0.f;
  #pragma unroll
  for (int i = 0; i < 8; ++i) s += scal[S_PAP + b * 256 + k0 + i * 32];
  sm[t] = s;
  __syncthreads();
  if (t < 8){
    float tot = 0.f;
    #pragma unroll
    for (int i = 0; i < 32; ++i) tot += sm[t * 32 + i];
    scal[S_ALPHA + t] = scal[S_RSOLD + t] / (tot + 1e-12f);
  }
}

// x(batch-major) += a p; r -= a Ap; accumulate rnew.rnew
__global__ void k_upd_nm(float* __restrict__ x_bm, float* __restrict__ r,
                         const float* __restrict__ p, const float* __restrict__ Ap,
                         float* __restrict__ scal, int n4tot, int Mn){
  if (*(const int*)(scal + S_FLAG)) return;
  int i = blockIdx.x * blockDim.x + threadIdx.x;
  int l = threadIdx.x & 63;
  float part = 0.f;
  if (i < n4tot){
    int v = i >> 4, rem = i & 15, b = rem >> 1, half = rem & 1;
    float al = scal[S_ALPHA + b];
    size_t xi = ((size_t)b * Mn + v) * 2 + half;
    f4 pv = ((const f4*)p)[i];
    f4 av = ((const f4*)Ap)[i];
    f4 xv = ((f4*)x_bm)[xi];
    f4 rv = ((f4*)r)[i];
    xv += al * pv;
    rv -= al * av;
    ((f4*)x_bm)[xi] = xv;
    ((f4*)r)[i] = rv;
    part = rv[0]*rv[0] + rv[1]*rv[1] + rv[2]*rv[2] + rv[3]*rv[3];
  }
  part += __shfl_xor(part, 1, 64);
  part += __shfl_xor(part, 16, 64);
  part += __shfl_xor(part, 32, 64);
  if ((l & 49) == 0)
    atomicAdd(&scal[S_RS + ((l >> 1) & 7) * 256 + (blockIdx.x & 255)], part);
}

// rsnew from S_RS; conv flag; BETA/RSOLD; zero slot arrays
__global__ void k_s2(float* __restrict__ scal){
  if (*(const int*)(scal + S_FLAG)) return;
  __shared__ float sm[256];
  __shared__ float rsn[8];
  int t = threadIdx.x;
  int b = t >> 5, k0 = t & 31;
  float s = 0.f;
  #pragma unroll
  for (int i = 0; i < 8; ++i) s += scal[S_RS + b * 256 + k0 + i * 32];
  sm[t] = s;
  __syncthreads();
  if (t < 8){
    float tot = 0.f;
    #pragma unroll
    for (int i = 0; i < 32; ++i) tot += sm[t * 32 + i];
    rsn[t] = tot;
  }
  __syncthreads();
  if (t == 0){
    float ssum = 0.f;
    for (int bb = 0; bb < 8; ++bb) ssum += rsn[bb];
    if (sqrtf(ssum / 8.0f) < TOL){
      *(int*)(scal + S_FLAG) = 1;   // freeze
    } else {
      for (int bb = 0; bb < 8; ++bb){
        scal[S_BETA + bb]  = rsn[bb] / (scal[S_RSOLD + bb] + 1e-12f);
        scal[S_RSOLD + bb] = rsn[bb];
      }
    }
  }
  __syncthreads();
  for (int i = t; i < 4096; i += 256) scal[S_PAP + i] = 0.f;
}

__global__ void k_pupd_nm(const float* __restrict__ r, float* __restrict__ p,
                          const float* __restrict__ scal, int n4tot){
  if (*(const int*)(scal + S_FLAG)) return;
  int i = blockIdx.x * blockDim.x + threadIdx.x;
  if (i >= n4tot) return;
  int b = (i >> 1) & 7;
  float be = scal[S_BETA + b];
  f4 rv = ((const f4*)r)[i];
  f4 pv = ((f4*)p)[i];
  pv = rv + be * pv;
  ((f4*)p)[i] = pv;
}

// ---------------- minimal fallback tier (batch-major, R-direct) ----------------
#define OS_RSOLD 0
#define OS_PAP   8
#define OS_RSNEW 16
#define OS_ALPHA 24
#define OS_BETA  32
#define OS_FLAG  40

__device__ __forceinline__ float blk_reduce_256(float v){
  __shared__ float sm[4];
  #pragma unroll
  for (int o = 32; o > 0; o >>= 1) v += __shfl_down(v, o, 64);
  int lane = threadIdx.x & 63, w = threadIdx.x >> 6;
  if (lane == 0) sm[w] = v;
  __syncthreads();
  return (threadIdx.x == 0) ? (sm[0] + sm[1] + sm[2] + sm[3]) : 0.f;
}

__global__ void k_setup_fb(float* scal){
  int i = blockIdx.x * blockDim.x + threadIdx.x;
  if (i < 64) scal[i] = 0.f;
}

__global__ void k_apinit(const float* __restrict__ in, float* __restrict__ out,
                         int n4tot, const int* __restrict__ flag){
  if (*flag) return;
  int j = blockIdx.x * blockDim.x + threadIdx.x;
  if (j < n4tot) ((f4*)out)[j] = ((const f4*)in)[j];
}

__global__ void k_mv_edge_fb(const float* __restrict__ Rs, const float* __restrict__ Rd,
                             const int* __restrict__ src, const int* __restrict__ dst,
                             const float* __restrict__ in, float* __restrict__ out,
                             int Mn, int E, const int* __restrict__ flag){
  if (*flag) return;
  int g  = blockIdx.x * blockDim.x + threadIdx.x;
  int wv = g >> 6, l = g & 63;
  int nw = (gridDim.x * blockDim.x) >> 6;
  int b = l >> 3, q = l & 7;
  for (int e = wv; e < E; e += nw){
    int s = src[e], t = dst[e];
    const f4* rs4 = (const f4*)(Rs + (size_t)e * 64 + q * 8);
    const f4* rd4 = (const f4*)(Rd + (size_t)e * 64 + q * 8);
    const f4* ps4 = (const f4*)(in + ((size_t)b * Mn + s) * 8);
    const f4* pd4 = (const f4*)(in + ((size_t)b * Mn + t) * 8);
    f4 ra0 = rs4[0], ra1 = rs4[1], pa0 = ps4[0], pa1 = ps4[1];
    f4 rb0 = rd4[0], rb1 = rd4[1], pb0 = pd4[0], pb1 = pd4[1];
    float re = dot8v(ra0, ra1, pa0, pa1) - dot8v(rb0, rb1, pb0, pb1);
    float cs = 0.f, cd = 0.f;
    #pragma unroll
    for (int a = 0; a < 8; ++a){
      float rea = __shfl(re, b * 8 + a, 64);
      cs += Rs[(size_t)e * 64 + a * 8 + q] * rea;
      cd += Rd[(size_t)e * 64 + a * 8 + q] * rea;
    }
    atomicAdd(&out[((size_t)b * Mn + s) * 8 + q],  LAM * cs);
    atomicAdd(&out[((size_t)b * Mn + t) * 8 + q], -LAM * cd);
  }
}

__global__ void k_init_o(const float* __restrict__ c0, const float* __restrict__ Ap,
                         float* __restrict__ x, float* __restrict__ r, float* __restrict__ p,
                         float* scal, int n4){
  int b = blockIdx.y;
  size_t base = (size_t)b * n4;
  int j = blockIdx.x * blockDim.x + threadIdx.x;
  float part = 0.f;
  if (j < n4){
    f4 cv = ((const f4*)c0)[base + j];
    f4 av = ((const f4*)Ap)[base + j];
    f4 rv = cv - av;
    ((f4*)x)[base + j] = cv;
    ((f4*)r)[base + j] = rv;
    ((f4*)p)[base + j] = rv;
    part = rv[0]*rv[0] + rv[1]*rv[1] + rv[2]*rv[2] + rv[3]*rv[3];
  }
  float tot = blk_reduce_256(part);
  if (threadIdx.x == 0) atomicAdd(&scal[OS_RSOLD + b], tot);
}

__global__ void k_dot_o(const float* __restrict__ p, const float* __restrict__ Ap,
                        float* scal, int n4){
  const int* flag = (const int*)(scal + OS_FLAG);
  if (*flag) return;
  int b = blockIdx.y;
  size_t base = (size_t)b * n4;
  int j = blockIdx.x * blockDim.x + threadIdx.x;
  float part = 0.f;
  if (j < n4){
    f4 pv = ((const f4*)p)[base + j];
    f4 av = ((const f4*)Ap)[base + j];
    part = pv[0]*av[0] + pv[1]*av[1] + pv[2]*av[2] + pv[3]*av[3];
  }
  float tot = blk_reduce_256(part);
  if (threadIdx.x == 0) atomicAdd(&scal[OS_PAP + b], tot);
}

__global__ void k_s1_o(float* scal){
  const int* flag = (const int*)(scal + OS_FLAG);
  if (*flag) return;
  int t = threadIdx.x;
  if (t < 8){
    scal[OS_ALPHA + t] = scal[OS_RSOLD + t] / (scal[OS_PAP + t] + 1e-12f);
    scal[OS_RSNEW + t] = 0.f;
  }
}

__global__ void k_upd_o(float* __restrict__ x, float* __restrict__ r,
                        const float* __restrict__ p, const float* __restrict__ Ap,
                        float* scal, int n4){
  const int* flag = (const int*)(scal + OS_FLAG);
  if (*flag) return;
  int b = blockIdx.y;
  size_t base = (size_t)b * n4;
  float al = scal[OS_ALPHA + b];
  int j = blockIdx.x * blockDim.x + threadIdx.x;
  float part = 0.f;
  if (j < n4){
    f4 pv = ((const f4*)p)[base + j];
    f4 av = ((const f4*)Ap)[base + j];
    f4 xv = ((f4*)x)[base + j];
    f4 rv = ((f4*)r)[base + j];
    xv += al * pv;
    rv -= al * av;
    ((f4*)x)[base + j] = xv;
    ((f4*)r)[base + j] = rv;
    part = rv[0]*rv[0] + rv[1]*rv[1] + rv[2]*rv[2] + rv[3]*rv[3];
  }
  float tot = blk_reduce_256(part);
  if (threadIdx.x == 0) atomicAdd(&scal[OS_RSNEW + b], tot);
}

__global__ void k_s2_o(float* scal){
  int* flag = (int*)(scal + OS_FLAG);
  if (*flag) return;
  if (threadIdx.x == 0){
    float ssum = 0.f;
    for (int bb = 0; bb < 8; ++bb) ssum += scal[OS_RSNEW + bb];
    if (sqrtf(ssum / 8.0f) < TOL){
      *flag = 1;
    } else {
      for (int bb = 0; bb < 8; ++bb){
        scal[OS_BETA + bb]  = scal[OS_RSNEW + bb] / (scal[OS_RSOLD + bb] + 1e-12f);
        scal[OS_RSOLD + bb] = scal[OS_RSNEW + bb];
        scal[OS_PAP + bb]   = 0.f;
      }
    }
  }
}

__global__ void k_pupd_o(const float* __restrict__ r, float* __restrict__ p,
                         float* scal, int n4){
  const int* flag = (const int*)(scal + OS_FLAG);
  if (*flag) return;
  int b = blockIdx.y;
  size_t base = (size_t)b * n4;
  float be = scal[OS_BETA + b];
  int j = blockIdx.x * blockDim.x + threadIdx.x;
  if (j < n4){
    f4 rv = ((const f4*)r)[base + j];
    f4 pv = ((f4*)p)[base + j];
    pv = rv + be * pv;
    ((f4*)p)[base + j] = pv;
  }
}

// ---------------- launch ----------------
extern "C" void kernel_launch(void* const* d_in, const int* in_sizes, int n_in,
                              void* d_out, int out_size, void* d_ws, size_t ws_size,
                              hipStream_t stream){
  const float* c0  = (const float*)d_in[0];
  const int*   src = (const int*)d_in[1];
  const int*   dst = (const int*)d_in[2];
  const float* Rs  = (const float*)d_in[3];
  const float* Rd  = (const float*)d_in[4];

  int N  = in_sizes[0];          // B*Mn*8 floats, B=8, d=8
  int Mn = N / 64;
  int E  = in_sizes[1];
  int n4tot = N / 4;
  int twoEM = 2 * E + Mn;        // neighbor slots + diagonal slots

  float* ws = (float*)d_ws;
  size_t off = 0;
  float* r    = ws + off;  off += N;
  float* p    = ws + off;  off += N;
  float* Ap   = ws + off;  off += N;
  float* scal = ws + off;  off += SCAL_F;
  int* rowptr = (int*)(ws + off);  off += (size_t)((Mn + 1 + 3) & ~3);
  int* cursor = (int*)(ws + off);  off += (size_t)((Mn + 3) & ~3);
  int* colA   = (int*)(ws + off);  off += (size_t)(twoEM + 8);
  int* esA    = (int*)(ws + off);  off += (size_t)twoEM;
  float* Bcsr = ws + off;  off += (size_t)(twoEM + 8) * 64;   // +8 pad slots
  size_t need_main = off * 4;

  int nb_vec  = (n4tot + 255) / 256;
  int nb_node = (Mn * 64 + 255) / 256;

  if (ws_size >= need_main){
    k_setup_nm<<<512, 256, 0, stream>>>(scal, cursor, Mn);
    k_deg  <<<1024, 256, 0, stream>>>(src, dst, cursor, E);
    k_scan <<<1, 1024, 0, stream>>>(cursor, rowptr, cursor, Mn, twoEM);
    k_fill <<<1024, 256, 0, stream>>>(src, dst, cursor, colA, esA, E);
    k_buildg<<<nb_node, 256, 0, stream>>>(Rs, Rd, rowptr, esA, Bcsr, colA, Mn);

    float* x_bm = (float*)d_out;
    k_perm<<<nb_vec, 256, 0, stream>>>(c0, p, Mn);   // p := c0 (node-major)
    k_mv<<<nb_node, 256, 0, stream>>>(Bcsr, rowptr, colA, p, Ap, scal, Mn);
    k_init_nm<<<nb_vec, 256, 0, stream>>>(p, Ap, r, x_bm, scal, n4tot, Mn);
    k_s0<<<1, 256, 0, stream>>>(scal);

    for (int it = 0; it < NIT; ++it){
      k_mv<<<nb_node, 256, 0, stream>>>(Bcsr, rowptr, colA, p, Ap, scal, Mn);
      k_alpha<<<1, 256, 0, stream>>>(scal);
      k_upd_nm<<<nb_vec, 256, 0, stream>>>(x_bm, r, p, Ap, scal, n4tot, Mn);
      k_s2<<<1, 256, 0, stream>>>(scal);
      k_pupd_nm<<<nb_vec, 256, 0, stream>>>(r, p, scal, n4tot);
    }
  } else {
    // fallback: batch-major R-direct (needs 3N+64 floats)
    float* fr    = ws;
    float* fp    = fr + N;
    float* fAp   = fp + N;
    float* fscal = fAp + N;
    const int* flagp = (const int*)(fscal + OS_FLAG);
    int n4 = Mn * 2;
    dim3 vgrid((n4 + 255) / 256, 8);
    int cb = (n4tot + 255) / 256;
    float* x = (float*)d_out;

    k_setup_fb<<<1, 64, 0, stream>>>(fscal);
    k_apinit<<<cb, 256, 0, stream>>>(c0, fAp, n4tot, flagp);
    k_mv_edge_fb<<<2048, 256, 0, stream>>>(Rs, Rd, src, dst, c0, fAp, Mn, E, flagp);
    k_init_o<<<vgrid, 256, 0, stream>>>(c0, fAp, x, fr, fp, fscal, n4);
    for (int it = 0; it < NIT; ++it){
      k_apinit<<<cb, 256, 0, stream>>>(fp, fAp, n4tot, flagp);
      k_mv_edge_fb<<<2048, 256, 0, stream>>>(Rs, Rd, src, dst, fp, fAp, Mn, E, flagp);
      k_dot_o<<<vgrid, 256, 0, stream>>>(fp, fAp, fscal, n4);
      k_s1_o<<<1, 64, 0, stream>>>(fscal);
      k_upd_o<<<vgrid, 256, 0, stream>>>(x, fr, fp, fAp, fscal, n4);
      k_s2_o<<<1, 64, 0, stream>>>(fscal);
      k_pupd_o<<<vgrid, 256, 0, stream>>>(fr, fp, fscal, n4);
    }
  }
}